// Round 4
// baseline (533.428 us; speedup 1.0000x reference)
//
#include <hip/hip_runtime.h>
#include <hip/hip_bf16.h>

// v5: single fused kernel, NON-cooperative (v3's cooperative launch never ran under
// graph capture -> output stayed memset-zero; absmax 6.22 = max|ref|).
//  Phase 1: v2's VERIFIED conv geometry + staging (inline pack->LDS, no T14 register
//    prefetch: v4 showed it spills at VGPR=64 -> +380 MB scratch traffic) with v4's
//    VERIFIED MFMA-linearity inner loop (5 MFMAs vs raw bf16 planes, f32 combine).
//  Grid barrier: spin on device-scope atomic counter. Safe: grid=512 = exactly
//    2 blocks/CU * 256 CU (LDS 75776 B caps at 2/CU), so ALL blocks co-resident.
//  Phase 2: per-block BN scale/shift from gstats (read via atomicAdd(p,0) ->
//    device-coherent, immune to stale local L2 copies).
//  Phase 3: BN+LeakyReLU in place on this block's OWN slice (self-written data,
//    no cross-block coherence needed; L2/L3-resident).

typedef __bf16 bf16x8 __attribute__((ext_vector_type(8)));
typedef float f32x4 __attribute__((ext_vector_type(4)));

__device__ __forceinline__ unsigned pack2(float a, float b) {
    __hip_bfloat162 h = __float22bfloat162_rn(make_float2(a, b));
    return *reinterpret_cast<unsigned*>(&h);
}

__global__ __launch_bounds__(512, 4) void conv_bn_fused(
    const float* __restrict__ xr, const float* __restrict__ xi,
    const float* __restrict__ filt, float* __restrict__ out,
    float* __restrict__ gstats, unsigned* __restrict__ done,
    const float* __restrict__ gr, const float* __restrict__ br,
    const float* __restrict__ gi, const float* __restrict__ bi)
{
    __shared__ __align__(16) unsigned short pqT[5 * 4096];     // 40960 B
    __shared__ __align__(16) unsigned short xsh[16 * 16 * 64]; // 32768 B
    __shared__ __align__(16) float statl[512];                 // 2048 B

    const int t = threadIdx.x;
    const int gid = blockIdx.x;
    const int oh = gid >> 8;             // o-half
    const int u  = (gid & 255) >> 1;     // 0..127
    const int vh = gid & 1;              // v-half
    const int obase = oh << 6;
    const int vbase0 = vh << 6;

    unsigned* pq32 = (unsigned*)pqT;
    unsigned* xs32 = (unsigned*)xsh;

    // ---- stage P/Q planes for (u, o-half): once per block
    const float au = 6.28318530717958647692f * (float)u / 128.0f;
    float su1, cu1, su2, cu2;
    __sincosf(au, &su1, &cu1);
    __sincosf(2.0f * au, &su2, &cu2);

    #pragma unroll
    for (int k = 0; k < 4; ++k) {            // 2048 (o, c-pair) items
        int i = t + k * 512;
        int o = i & 63;                       // coalesced filt reads
        int cp = i >> 6;                      // 0..31 (c = 2cp, 2cp+1)
        int g0 = (2 * cp) * 128 + obase + o;
        int g1 = g0 + 128;
        unsigned wd = o * 32 + (((cp >> 2) ^ (o & 7)) << 2) + (cp & 3); // swizzled dword
        #pragma unroll
        for (int b = 0; b < 3; ++b) {
            float f0a = filt[b * 8192 + g0],       f0b = filt[b * 8192 + g1];
            float f1a = filt[(3 + b) * 8192 + g0], f1b = filt[(3 + b) * 8192 + g1];
            float f2a = filt[(6 + b) * 8192 + g0], f2b = filt[(6 + b) * 8192 + g1];
            float Pa = fmaf(cu2, f2a, fmaf(cu1, f1a, f0a));
            float Pb = fmaf(cu2, f2b, fmaf(cu1, f1b, f0b));
            pq32[b * 2048 + wd] = pack2(Pa, Pb);
            if (b > 0) {
                float Qa = fmaf(su2, f2a, su1 * f1a);
                float Qb = fmaf(su2, f2b, su1 * f1b);
                pq32[(b + 2) * 2048 + wd] = pack2(Qa, Qb);
            }
        }
    }

    // ---- wave assignment
    const int wave = t >> 6;
    const int lane = t & 63;
    const int vg   = wave >> 1;       // 4 v's per wave (chunk-local)
    const int nth  = wave & 1;        // o-tile pair: ot = nth*2 + ntl
    const int ln15 = lane & 15;
    const int q    = lane >> 4;
    const int swz  = ln15 & 7;
    const int part = q >> 1;
    const int nbase = (q & 1) * 4;

    const int sv = t >> 5;            // staging: chunk-local v
    const int scp = t & 31;           // staging: c-pair

    float ssum[2] = {0.f, 0.f}, ssq[2] = {0.f, 0.f};

    #pragma unroll 1
    for (int chk = 0; chk < 4; ++chk) {
        // ---- stage x' chunk (v2 verified path, inline: no long-lived prefetch regs)
        {
            const int vglob = vbase0 + chk * 16 + sv;
            #pragma unroll
            for (int n = 0; n < 8; ++n) {
                size_t gi = (((size_t)(n * 128 + u)) * 128 + vglob) * 64 + 2 * scp;
                float2 r  = *(const float2*)(xr + gi);
                float2 m2 = *(const float2*)(xi + gi);
                unsigned rp = pack2(r.x + m2.x, r.y + m2.y);
                unsigned ip = pack2(m2.x - r.x, m2.y - r.y);
                unsigned base = (sv * 16 + n) * 32 + (((scp >> 2) ^ (n & 7)) << 2) + (scp & 3);
                xs32[base] = rp;               // np = n      (r+i)
                xs32[base + 256] = ip;         // np = 8+n    (i-r)
            }
        }
        __syncthreads();

        // ---- per-v trig
        float cv1[4], cv2[4], nsv1[4], nsv2[4];
        #pragma unroll
        for (int vj = 0; vj < 4; ++vj) {
            float av = 6.28318530717958647692f *
                       (float)(vbase0 + chk * 16 + vg * 4 + vj) / 128.0f;
            float s1, c1, s2, c2;
            __sincosf(av, &s1, &c1);
            __sincosf(2.0f * av, &s2, &c2);
            cv1[vj] = c1; cv2[vj] = c2; nsv1[vj] = -s1; nsv2[vj] = -s2;
        }

        // ---- main: 5 plane-MFMAs per (ntl,vj), f32 combine (v4 verified)
        #pragma unroll
        for (int ntl = 0; ntl < 2; ++ntl) {
            const int o_loc = (nth * 2 + ntl) * 16 + ln15;
            const unsigned short* prow = &pqT[o_loc * 64];

            bf16x8 pf[2][5];
            #pragma unroll
            for (int ks = 0; ks < 2; ++ks) {
                const int foff = (((ks * 4 + q) ^ swz) << 3);
                #pragma unroll
                for (int p = 0; p < 5; ++p)
                    pf[ks][p] = __builtin_bit_cast(bf16x8,
                        *(const uint4*)(prow + p * 4096 + foff));
            }

            #pragma unroll
            for (int vj = 0; vj < 4; ++vj) {
                const unsigned short* xrow = &xsh[((vg * 4 + vj) * 16 + ln15) * 64];
                bf16x8 af0 = __builtin_bit_cast(bf16x8,
                    *(const uint4*)(xrow + ((q ^ swz) << 3)));
                bf16x8 af1 = __builtin_bit_cast(bf16x8,
                    *(const uint4*)(xrow + (((4 + q) ^ swz) << 3)));

                f32x4 tp[5];
                #pragma unroll
                for (int p = 0; p < 5; ++p) {
                    f32x4 z = (f32x4){0.f, 0.f, 0.f, 0.f};
                    z = __builtin_amdgcn_mfma_f32_16x16x32_bf16(af0, pf[0][p], z, 0, 0, 0);
                    tp[p] = __builtin_amdgcn_mfma_f32_16x16x32_bf16(af1, pf[1][p], z, 0, 0, 0);
                }

                const int vglob = vbase0 + chk * 16 + vg * 4 + vj;
                size_t base = (size_t)part * 16777216 + (size_t)nbase * 2097152
                            + ((size_t)(u * 128 + vglob)) * 128 + obase + o_loc;
                #pragma unroll
                for (int r = 0; r < 4; ++r) {
                    float y = fmaf(cv1[vj], tp[1][r], tp[0][r]);
                    y = fmaf(cv2[vj], tp[2][r], y);
                    y = fmaf(nsv1[vj], tp[3][r], y);
                    y = fmaf(nsv2[vj], tp[4][r], y);
                    out[base + (size_t)r * 2097152] = y;   // cached: keep in L3
                    ssum[ntl] += y;
                    ssq[ntl] = fmaf(y, y, ssq[ntl]);
                }
            }
        }
        __syncthreads();    // xsh fully consumed before next chunk's staging
    }

    // ---- block-level stats reduction -> global atomics (device scope)
    statl[t] = 0.f;
    __syncthreads();
    #pragma unroll
    for (int ntl = 0; ntl < 2; ++ntl) {
        int chn = part * 128 + obase + (nth * 2 + ntl) * 16 + ln15;
        atomicAdd(&statl[chn], ssum[ntl]);
        atomicAdd(&statl[256 + chn], ssq[ntl]);
    }
    __syncthreads();
    atomicAdd(&gstats[t], statl[t]);

    // ================= grid-wide spin barrier (all 512 blocks resident) =========
    __syncthreads();                       // all block's gstats atomics retired
    if (t == 0) {
        __threadfence();
        atomicAdd(done, 1u);
        while (atomicAdd(done, 0u) < 512u) {
            __builtin_amdgcn_s_sleep(2);
        }
        __threadfence();
    }
    __syncthreads();

    // ---- phase 2: all 256 channels' scale/shift into LDS (coherent atomic reads)
    if (t < 256) {
        int pp = t >> 7, o = t & 127;
        const float inv = 1.0f / 131072.0f;
        float s0 = atomicAdd(&gstats[t], 0.0f);
        float s1 = atomicAdd(&gstats[256 + t], 0.0f);
        float mean = s0 * inv;
        float var  = s1 * inv - mean * mean;
        float g = pp ? gi[o] : gr[o];
        float b = pp ? bi[o] : br[o];
        float s = g * rsqrtf(var + 1e-3f);
        statl[t]       = s;
        statl[256 + t] = b - mean * s;
    }
    __syncthreads();

    // ---- phase 3: BN+LeakyReLU on this block's own slice, in place
    const f32x4* scv = (const f32x4*)statl;          // [64] scale vectors
    const f32x4* shv = (const f32x4*)(statl + 256);  // [64] shift vectors
    const int ob4 = obase >> 2;
    #pragma unroll 4
    for (int it2 = 0; it2 < 32; ++it2) {
        int idx = t + it2 * 512;           // 0..16383 over [part][n][v][o/4]
        int oq = idx & 15;
        int vv = (idx >> 4) & 63;
        int nn = (idx >> 10) & 7;
        int pp = idx >> 13;
        size_t e = ((((size_t)(pp * 8 + nn) * 128 + u) * 128
                   + (size_t)(vbase0 + vv)) << 7) + (size_t)(obase + oq * 4);
        f32x4 x = *(const f32x4*)(out + e);
        f32x4 sc = scv[pp * 32 + ob4 + oq];
        f32x4 sh = shv[pp * 32 + ob4 + oq];
        f32x4 y;
        #pragma unroll
        for (int r = 0; r < 4; ++r) {
            float w = fmaf(x[r], sc[r], sh[r]);
            y[r] = w >= 0.0f ? w : 0.2f * w;
        }
        *(f32x4*)(out + e) = y;
    }
}

extern "C" void kernel_launch(void* const* d_in, const int* in_sizes, int n_in,
                              void* d_out, int out_size, void* d_ws, size_t ws_size,
                              hipStream_t stream)
{
    const float* xr   = (const float*)d_in[0];
    const float* xi   = (const float*)d_in[1];
    const float* filt = (const float*)d_in[2];
    const float* gr   = (const float*)d_in[3];
    const float* br   = (const float*)d_in[4];
    const float* gi   = (const float*)d_in[5];
    const float* bi   = (const float*)d_in[6];
    float* out = (float*)d_out;
    float* ws  = (float*)d_ws;

    float* gstats  = ws;                    // 512 floats
    unsigned* done = (unsigned*)(ws + 512); // 1 uint

    (void)hipMemsetAsync(ws, 0, 516 * sizeof(float), stream);
    conv_bn_fused<<<dim3(512), dim3(512), 0, stream>>>(
        xr, xi, filt, out, gstats, done, gr, br, gi, bi);
}